// Round 2
// baseline (269.471 us; speedup 1.0000x reference)
//
#include <hip/hip_runtime.h>

typedef unsigned short u16;
using bf16x8 = __attribute__((ext_vector_type(8))) short;   // 8 bf16 (4 VGPRs)
using f32x4  = __attribute__((ext_vector_type(4))) float;   // 4 fp32

__device__ __forceinline__ u16 f2b(float f) {
    __bf16 h = (__bf16)f;
    return __builtin_bit_cast(unsigned short, h);
}
__device__ __forceinline__ float b2f(u16 u) {
    return (float)__builtin_bit_cast(__bf16, u);
}
__device__ __forceinline__ void gload16(const u16* g, const u16* l) {
    __builtin_amdgcn_global_load_lds(
        (const __attribute__((address_space(1))) unsigned int*)g,
        (__attribute__((address_space(3))) unsigned int*)l, 16, 0, 0);
}
// chunk swizzle: q' = q ^ ((row ^ (row>>2)) & 3)  — involution, 2-way(free) ds_read conflicts
__device__ __forceinline__ int swz(int row, int q) { return q ^ ((row ^ (row >> 2)) & 3); }

// C = A * B^T (A: MxK rm, B: NxK rm), bf16 in, fp32 MFMA accum.
// 8-phase counted-vmcnt pipeline: BM=256, BN=NBLK*64, BK=64 (2 K-halves of 32),
// 8 waves (2M x 4N), per-wave 128 x NBLK*16. LDS: 2 parity slots x 2 K-halves.
// Phase (qm,kh) order (0,0)(1,0)(0,1)(1,1); issue {p1:B-K0(t+1) p2:A-K1(t+1)
// p3:B-K1(t+1) p4:A-K0(t+2)}; vmcnt(VMC) at p2/p4 => 3 half-tiles in flight.
// Overwrite safety: each region's last read is >=1 barrier before its overwrite issue.
// MODE 0: C_bf16 = acc + bias[col]
// MODE 2: P_bf16 = exp2(acc*wk[col]); atomicAdd(rowsum[row], sum of bf16-rounded P)
// MODE 3: C_f32  = acc / rowsum[row]
template<int MODE, int NBLK>
__global__ __launch_bounds__(512, 2)
void gemm8(const u16* __restrict__ A, const u16* __restrict__ B,
           void* __restrict__ Cv, const float* __restrict__ aux,
           float* __restrict__ rowsum,
           int K, int lda, int ldb, int ldc,
           long strA, long strB, long strC, long strAux, long strRS)
{
    constexpr int BR  = NBLK * 64;                 // B tile rows (= C cols per block)
    constexpr int VMC = (NBLK == 4) ? 6 : 5;       // loads in newest 3 half-tiles
    __shared__ __align__(16) u16 sA[2][2][256 * 32];
    __shared__ __align__(16) u16 sB[2][2][BR * 32];

    const int tid  = threadIdx.x;
    const int lane = tid & 63;
    const int wave = tid >> 6;                     // 0..7
    const int wm = wave >> 2, wn = wave & 3;       // 2M x 4N
    const int l16 = lane & 15, qld = lane >> 4;

    // XCD-chunked bijective swizzle of (bx,by) within each z (nxy % 8 == 0 for all grids)
    const int gx = gridDim.x, gy = gridDim.y;
    const int nxy = gx * gy;
    int li = blockIdx.y * gx + blockIdx.x;
    li = (li & 7) * (nxy >> 3) + (li >> 3);
    const int bx = li % gx, by = li / gx;
    const int bn0 = bx * BR, bm0 = by * 256;
    const long z = blockIdx.z;

    const u16* Ab = A + z * strA + (long)bm0 * lda;
    const u16* Bb = B + z * strB + (long)bn0 * ldb;
    const float* auxp = aux + z * strAux;

    // staging: chunk ci <-> (row=ci>>2, q'=ci&3); source pre-swizzled so LDS is
    // linear in thread order (global_load_lds writes base + lane*16)
    const int cA0 = tid, cA1 = 512 + tid;
    const u16* srcA0 = Ab + (long)(cA0 >> 2) * lda + swz(cA0 >> 2, cA0 & 3) * 8;
    const u16* srcA1 = Ab + (long)(cA1 >> 2) * lda + swz(cA1 >> 2, cA1 & 3) * 8;
    const int cB1 = (NBLK == 4) ? cA1 : cA0;
    const u16* srcB0 = Bb + (long)(cA0 >> 2) * ldb + swz(cA0 >> 2, cA0 & 3) * 8;
    const u16* srcB1 = Bb + (long)(cB1 >> 2) * ldb + swz(cB1 >> 2, cB1 & 3) * 8;
    const int wch = (tid & ~63) * 8;               // wave-uniform LDS offset (u16)

#define STAGE_A(sl, kh, colb) do { \
    gload16(srcA0 + (colb), &sA[sl][kh][wch]); \
    gload16(srcA1 + (colb), &sA[sl][kh][wch + 4096]); } while (0)
#define STAGE_B(sl, kh, colb) do { \
    gload16(srcB0 + (colb), &sB[sl][kh][wch]); \
    if constexpr (NBLK == 4) { gload16(srcB1 + (colb), &sB[sl][kh][wch + 4096]); } } while (0)

    // per-thread fragment LDS offsets (u16 units), statically indexed after unroll
    int offA[8], offB[NBLK];
#pragma unroll
    for (int mf = 0; mf < 8; ++mf) {
        const int row = wm * 128 + mf * 16 + l16;
        offA[mf] = row * 32 + swz(row, qld) * 8;
    }
#pragma unroll
    for (int n = 0; n < NBLK; ++n) {
        const int row = wn * (NBLK * 16) + n * 16 + l16;
        offB[n] = row * 32 + swz(row, qld) * 8;
    }

    f32x4 acc[8][NBLK] = {};
    const int NT = K >> 6;

    // prologue: tile0 fully + A-K0(1); wait so only A-K0(1) may remain in flight
    STAGE_A(0, 0, 0);
    STAGE_B(0, 0, 0);
    STAGE_A(0, 1, 32);
    STAGE_B(0, 1, 32);
    if (NT > 1) STAGE_A(1, 0, 64);
    asm volatile("s_waitcnt vmcnt(2)" ::: "memory");
    __builtin_amdgcn_sched_barrier(0);
    asm volatile("s_barrier" ::: "memory");

    for (int t = 0; t < NT; ++t) {
        const int s = t & 1, s1 = s ^ 1;
        const int kc1 = (t + 1) << 6;
        const bool i1 = (t + 1 < NT), i2 = (t + 2 < NT);
        const bool tail = (t >= NT - 2);

        bf16x8 afr[4], bfr[NBLK];
        // ---------- phase 1: qm=0, kh=0 ----------
#pragma unroll
        for (int j = 0; j < 4; ++j) afr[j] = *(const bf16x8*)&sA[s][0][offA[j]];
#pragma unroll
        for (int n = 0; n < NBLK; ++n) bfr[n] = *(const bf16x8*)&sB[s][0][offB[n]];
        if (i1) STAGE_B(s1, 0, kc1);
        asm volatile("s_barrier" ::: "memory");
        __builtin_amdgcn_s_setprio(1);
#pragma unroll
        for (int j = 0; j < 4; ++j)
#pragma unroll
            for (int n = 0; n < NBLK; ++n)
                acc[j][n] = __builtin_amdgcn_mfma_f32_16x16x32_bf16(afr[j], bfr[n], acc[j][n], 0, 0, 0);
        __builtin_amdgcn_s_setprio(0);
        asm volatile("s_waitcnt lgkmcnt(0)" ::: "memory");
        __builtin_amdgcn_sched_barrier(0);
        asm volatile("s_barrier" ::: "memory");

        // ---------- phase 2: qm=1, kh=0 ----------
#pragma unroll
        for (int j = 0; j < 4; ++j) afr[j] = *(const bf16x8*)&sA[s][0][offA[4 + j]];
        if (i1) STAGE_A(s1, 1, kc1 + 32);
        asm volatile("s_barrier" ::: "memory");
        __builtin_amdgcn_s_setprio(1);
#pragma unroll
        for (int j = 0; j < 4; ++j)
#pragma unroll
            for (int n = 0; n < NBLK; ++n)
                acc[4 + j][n] = __builtin_amdgcn_mfma_f32_16x16x32_bf16(afr[j], bfr[n], acc[4 + j][n], 0, 0, 0);
        __builtin_amdgcn_s_setprio(0);
        if (tail) asm volatile("s_waitcnt vmcnt(0)" ::: "memory");
        else      asm volatile("s_waitcnt vmcnt(%0)" :: "i"(VMC) : "memory");
        asm volatile("s_waitcnt lgkmcnt(0)" ::: "memory");
        __builtin_amdgcn_sched_barrier(0);
        asm volatile("s_barrier" ::: "memory");

        // ---------- phase 3: qm=0, kh=1 ----------
#pragma unroll
        for (int j = 0; j < 4; ++j) afr[j] = *(const bf16x8*)&sA[s][1][offA[j]];
#pragma unroll
        for (int n = 0; n < NBLK; ++n) bfr[n] = *(const bf16x8*)&sB[s][1][offB[n]];
        if (i1) STAGE_B(s1, 1, kc1 + 32);
        asm volatile("s_barrier" ::: "memory");
        __builtin_amdgcn_s_setprio(1);
#pragma unroll
        for (int j = 0; j < 4; ++j)
#pragma unroll
            for (int n = 0; n < NBLK; ++n)
                acc[j][n] = __builtin_amdgcn_mfma_f32_16x16x32_bf16(afr[j], bfr[n], acc[j][n], 0, 0, 0);
        __builtin_amdgcn_s_setprio(0);
        asm volatile("s_waitcnt lgkmcnt(0)" ::: "memory");
        __builtin_amdgcn_sched_barrier(0);
        asm volatile("s_barrier" ::: "memory");

        // ---------- phase 4: qm=1, kh=1 ----------
#pragma unroll
        for (int j = 0; j < 4; ++j) afr[j] = *(const bf16x8*)&sA[s][1][offA[4 + j]];
        if (i2) STAGE_A(s, 0, kc1 + 64);   // A-K0(t+2) into current slot (region's reads ended @p2)
        asm volatile("s_barrier" ::: "memory");
        __builtin_amdgcn_s_setprio(1);
#pragma unroll
        for (int j = 0; j < 4; ++j)
#pragma unroll
            for (int n = 0; n < NBLK; ++n)
                acc[4 + j][n] = __builtin_amdgcn_mfma_f32_16x16x32_bf16(afr[j], bfr[n], acc[4 + j][n], 0, 0, 0);
        __builtin_amdgcn_s_setprio(0);
        if (tail) asm volatile("s_waitcnt vmcnt(0)" ::: "memory");
        else      asm volatile("s_waitcnt vmcnt(%0)" :: "i"(VMC) : "memory");
        asm volatile("s_waitcnt lgkmcnt(0)" ::: "memory");
        __builtin_amdgcn_sched_barrier(0);
        asm volatile("s_barrier" ::: "memory");
    }
#undef STAGE_A
#undef STAGE_B

    // C/D layout: col = lane&15, row = (lane>>4)*4 + reg
    const int rg = lane >> 4;
    const int orow0 = bm0 + wm * 128;
    const int ocol0 = bn0 + wn * (NBLK * 16);

    if constexpr (MODE == 0) {
        u16* Co = (u16*)Cv + z * strC;
        float bias[NBLK];
#pragma unroll
        for (int n = 0; n < NBLK; ++n) bias[n] = auxp[ocol0 + n * 16 + l16];
#pragma unroll
        for (int mf = 0; mf < 8; ++mf)
#pragma unroll
            for (int n = 0; n < NBLK; ++n) {
                const int col = ocol0 + n * 16 + l16;
#pragma unroll
                for (int r = 0; r < 4; ++r) {
                    const int row = orow0 + mf * 16 + rg * 4 + r;
                    Co[(long)row * ldc + col] = f2b(acc[mf][n][r] + bias[n]);
                }
            }
    } else if constexpr (MODE == 2) {
        u16* Co = (u16*)Cv + z * strC;
        float* rsp = rowsum + z * strRS;
        float wkn[NBLK];
#pragma unroll
        for (int n = 0; n < NBLK; ++n) wkn[n] = auxp[ocol0 + n * 16 + l16];
#pragma unroll
        for (int mf = 0; mf < 8; ++mf)
#pragma unroll
            for (int r = 0; r < 4; ++r) {
                const int row = orow0 + mf * 16 + rg * 4 + r;
                float partial = 0.f;
#pragma unroll
                for (int n = 0; n < NBLK; ++n) {
                    const int col = ocol0 + n * 16 + l16;
                    const float p = exp2f(acc[mf][n][r] * wkn[n]);
                    const u16 pb = f2b(p);
                    Co[(long)row * ldc + col] = pb;
                    partial += b2f(pb);   // denominator from bf16-rounded P
                }
                partial += __shfl_xor(partial, 1);
                partial += __shfl_xor(partial, 2);
                partial += __shfl_xor(partial, 4);
                partial += __shfl_xor(partial, 8);
                if (l16 == 0) atomicAdd(&rsp[row], partial);
            }
    } else {  // MODE 3
        float* Co = (float*)Cv + z * strC;
#pragma unroll
        for (int mf = 0; mf < 8; ++mf)
#pragma unroll
            for (int r = 0; r < 4; ++r) {
                const int row = orow0 + mf * 16 + rg * 4 + r;
                const float inv = 1.0f / auxp[row];
#pragma unroll
                for (int n = 0; n < NBLK; ++n) {
                    const int col = ocol0 + n * 16 + l16;
                    Co[(long)row * ldc + col] = acc[mf][n][r] * inv;
                }
            }
    }
}

__global__ void cvt_bf16(const float* __restrict__ in, u16* __restrict__ out, int n4) {
    const int i = blockIdx.x * 256 + threadIdx.x;
    if (i >= n4) return;
    const float4 f = ((const float4*)in)[i];
    ushort4 o;
    o.x = f2b(f.x); o.y = f2b(f.y); o.z = f2b(f.z); o.w = f2b(f.w);
    ((ushort4*)out)[i] = o;
}

__global__ void wk_kernel(const float* __restrict__ eig, float* __restrict__ wk, int n) {
    const int i = blockIdx.x * 256 + threadIdx.x;
    if (i >= n) return;
    const float s = 1.0f / (1.0f + expf(-eig[i]));
    wk[i] = s * (float)(1.4426950408889634 / 22.627416997969522);  // log2(e)/sqrt(512)
}

// V slice of qkvC [16384][1536] (cols 1024..1535) -> Vt [8][512][2048] bf16
__global__ __launch_bounds__(256)
void transpose_v(const u16* __restrict__ Vq, u16* __restrict__ Vt) {
    __shared__ u16 t[64][65];
    const int tid = threadIdx.x;
    const int d0  = blockIdx.x * 64;
    const int bs0 = blockIdx.y * 64;
#pragma unroll
    for (int i = 0; i < 16; ++i) {
        const int idx = i * 256 + tid;
        const int r = idx >> 6, c = idx & 63;
        t[r][c] = Vq[(long)(bs0 + r) * 1536 + d0 + c];
    }
    __syncthreads();
    const long b = bs0 >> 11;
    const int s0 = bs0 & 2047;
#pragma unroll
    for (int i = 0; i < 16; ++i) {
        const int idx = i * 256 + tid;
        const int dch = idx >> 6, ss = idx & 63;
        Vt[(b * 512 + d0 + dch) * 2048 + s0 + ss] = t[ss][dch];
    }
}

extern "C" void kernel_launch(void* const* d_in, const int* in_sizes, int n_in,
                              void* d_out, int out_size, void* d_ws, size_t ws_size,
                              hipStream_t stream) {
    const float* x  = (const float*)d_in[0];
    const float* ev = (const float*)d_in[1];
    const float* Wq = (const float*)d_in[2];
    const float* bq = (const float*)d_in[3];
    const float* Wk = (const float*)d_in[4];
    const float* bk = (const float*)d_in[5];
    const float* Wv = (const float*)d_in[6];
    const float* bv = (const float*)d_in[7];
    float* out = (float*)d_out;

    char* ws = (char*)d_ws;
    u16*   P      = (u16*)(ws);                      // 64 MB  P bf16 [8][2048][2048]
    u16*   xb     = (u16*)(ws + (64ul << 20));       // 16 MB  x bf16 [16384][512]
    u16*   qkvC   = (u16*)(ws + (80ul << 20));       // 48 MB  [16384][1536] = Q|K|V
    u16*   Vt     = (u16*)(ws + (128ul << 20));      // 16 MB  V^T bf16 [8][512][2048]
    u16*   Wb     = (u16*)(ws + (144ul << 20));      // 1.5 MB Wq|Wk|Wv bf16 [1536][512]
    float* biasb  = (float*)(ws + (146ul << 20));    // 6 KB   concat bias [1536]
    float* wk     = (float*)(ws + (146ul << 20) + 65536);   // 64 KB
    float* rowsum = (float*)(ws + (146ul << 20) + 131072);  // 64 KB

    cvt_bf16<<<dim3(8192), dim3(256), 0, stream>>>(x, xb, 2097152);
    cvt_bf16<<<dim3(256),  dim3(256), 0, stream>>>(Wq, Wb,          65536);
    cvt_bf16<<<dim3(256),  dim3(256), 0, stream>>>(Wk, Wb + 262144, 65536);
    cvt_bf16<<<dim3(256),  dim3(256), 0, stream>>>(Wv, Wb + 524288, 65536);
    hipMemcpyAsync(biasb,        bq, 512 * 4, hipMemcpyDeviceToDevice, stream);
    hipMemcpyAsync(biasb + 512,  bk, 512 * 4, hipMemcpyDeviceToDevice, stream);
    hipMemcpyAsync(biasb + 1024, bv, 512 * 4, hipMemcpyDeviceToDevice, stream);
    wk_kernel<<<dim3(64), dim3(256), 0, stream>>>(ev, wk, 16384);
    hipMemsetAsync(rowsum, 0, 65536, stream);

    // QKV projection: M=16384, N=1536 (concat), K=512
    gemm8<0, 2><<<dim3(12, 64, 1), dim3(512), 0, stream>>>(
        xb, Wb, qkvC, biasb, nullptr,
        512, 512, 512, 1536,
        0L, 0L, 0L, 0L, 0L);

    transpose_v<<<dim3(8, 256), dim3(256), 0, stream>>>(qkvC + 1024, Vt);

    // scores + exp: per batch, M=N=2048, K=512
    gemm8<2, 4><<<dim3(8, 8, 8), dim3(512), 0, stream>>>(
        qkvC, qkvC + 512, P, wk, rowsum,
        512, 1536, 1536, 2048,
        3145728L, 3145728L, 4194304L, 2048L, 2048L);

    // PV: per batch, M=2048, N=512, K=2048
    gemm8<3, 2><<<dim3(4, 8, 8), dim3(512), 0, stream>>>(
        P, Vt, out, rowsum, nullptr,
        2048, 2048, 2048, 512,
        4194304L, 1048576L, 1048576L, 2048L, 0L);
}